// Round 5
// baseline (161.378 us; speedup 1.0000x reference)
//
#include <hip/hip_runtime.h>
#include <stdint.h>

#define DMAX 80
#define BLK  256

typedef float f32x4 __attribute__((ext_vector_type(4)));

// ---------------------------------------------------------------------------
// Setup kernel:
//  - thread 0: detect mask dtype (bool8 / int32 / float32) using known m,
//    compact selected indices into idx_out[0..m).
//  - grid-stride over pair ranks p in [0,P), P = m(m+1)/2:
//      pairtab[p] = i | j<<8
//      coltab[c]  = p | k<<16  where column c = pps[p] * xsel[k]
//        [0,m)      order-1: p = P (sentinel pps=1), k = c
//        [m, m+P)   order-2: p = rank,               k = m (sentinel x=1)
//        [m+P, T)   order-3: run over k in [j, m) for each pair (i,j)
// ---------------------------------------------------------------------------
__global__ void maskde_setup(const void* __restrict__ mask_raw, int m,
                             int* __restrict__ idx_out,
                             uint32_t* __restrict__ pairtab,
                             uint32_t* __restrict__ coltab, int P) {
    int tid = blockIdx.x * blockDim.x + threadIdx.x;
    if (tid == 0) {
        const uint8_t* b8  = (const uint8_t*)mask_raw;
        const int*     b32 = (const int*)mask_raw;
        const float*   bf  = (const float*)mask_raw;
        int cnt = 0; bool ok = true;
        for (int i = 0; i < DMAX; ++i) { uint8_t v = b8[i]; if (v > 1) ok = false; cnt += (v != 0); }
        int mode;
        if (ok && cnt == m) {
            mode = 0;
        } else {
            cnt = 0; ok = true;
            for (int i = 0; i < DMAX; ++i) { int v = b32[i]; if (v != 0 && v != 1) ok = false; cnt += (v != 0); }
            mode = (ok && cnt == m) ? 1 : 2;
        }
        int k = 0;
        for (int i = 0; i < DMAX && k < m; ++i) {
            bool on = (mode == 0) ? (b8[i] != 0)
                    : (mode == 1) ? (b32[i] != 0)
                                  : (bf[i] != 0.0f);
            if (on) idx_out[k++] = i;
        }
    }

    int stride = gridDim.x * blockDim.x;
    for (int p = tid; p < P; p += stride) {
        int rem = p, i = 0;
        while (rem >= m - i) { rem -= (m - i); ++i; }
        int j = i + rem;

        pairtab[p] = (uint32_t)i | ((uint32_t)j << 8);

        if (p < m)
            coltab[p] = (uint32_t)P | ((uint32_t)p << 16);      // order-1
        coltab[m + p] = (uint32_t)p | ((uint32_t)m << 16);      // order-2

        // order-3 run for pair (i,j)
        int mi = m - i;
        long long Si  = ((long long)m * (m + 1) * (m + 2)
                       - (long long)mi * (mi + 1) * (mi + 2)) / 6;
        int Rij = ((m - i) + (m - j + 1)) * (j - i) / 2;
        uint32_t* t3 = coltab + m + P + Si + Rij;
        for (int k3 = j; k3 < m; ++k3)
            t3[k3 - j] = (uint32_t)p | ((uint32_t)k3 << 16);
    }
}

// ---------------------------------------------------------------------------
// Build shifted table copies: copy s (s=1..3) at coltab + s*tpad holds
// copy_s[q] = coltab[q + s], so a row whose float4 region starts at column
// s can load 16B-aligned uint4 table entries.  Padding -> safe sentinel.
// ---------------------------------------------------------------------------
__global__ void maskde_copies(uint32_t* __restrict__ coltab, int tpad, int T,
                              int m, int P) {
    int q = blockIdx.x * blockDim.x + threadIdx.x;
    int total = 3 * tpad;
    uint32_t sentinel = (uint32_t)P | ((uint32_t)m << 16);  // pps=1 * xls=1
    for (; q < total; q += gridDim.x * blockDim.x) {
        int s   = 1 + q / tpad;
        int off = q - (s - 1) * tpad;
        uint32_t v = (off + s < T) ? coltab[off + s] : sentinel;
        coltab[s * tpad + off] = v;
    }
}

// ---------------------------------------------------------------------------
// Main kernel: one block per row.
//   LDS: xls[m+1] (+1.0 sentinel), pps[P+1] pair products (+1.0 sentinel).
//   Each output element = pps[p] * xls[k]: 2 LDS reads + 1 mul.
//   Main loop: one aligned uint4 table load + one aligned NONTEMPORAL
//   float4 store (streaming, no L2 write-allocate).
// ---------------------------------------------------------------------------
__global__ __launch_bounds__(BLK) void
maskde_expand(const float* __restrict__ x, const int* __restrict__ idx,
              const uint32_t* __restrict__ pairtab,
              const uint32_t* __restrict__ coltab, int tpad,
              float* __restrict__ out, int m, int T, int P) {
    __shared__ float xls[DMAX + 1];
    extern __shared__ float pps[];   // P+1 floats

    const int row = blockIdx.x;
    const int tid = threadIdx.x;

    if (tid <= m)
        xls[tid] = (tid < m) ? x[row * DMAX + idx[tid]] : 1.0f;
    __syncthreads();

    for (int p = tid; p <= P; p += BLK) {
        float v = 1.0f;
        if (p < P) {
            uint32_t ij = pairtab[p];
            v = xls[ij & 0xFF] * xls[(ij >> 8) & 0xFF];
        }
        pps[p] = v;
    }
    __syncthreads();

    float* orow = out + (size_t)row * (size_t)T;
    uintptr_t a0 = (uintptr_t)orow;
    int k0 = (int)(((16 - (a0 & 15)) & 15) >> 2);
    if (k0 > T) k0 = T;

    // scalar prologue (base table copy)
    if (tid < k0) {
        uint32_t e = coltab[tid];
        __builtin_nontemporal_store(pps[e & 0xFFFF] * xls[e >> 16], orow + tid);
    }

    const int nv = (T - k0) >> 2;
    // shifted copy k0: entry q corresponds to column q + k0, 16B aligned
    const uint4* tbv = (const uint4*)(coltab + (size_t)k0 * (size_t)tpad);
    float* ovbase = orow + k0;

    for (int v = tid; v < nv; v += BLK) {
        uint4 e = tbv[v];
        f32x4 o;
        o.x = pps[e.x & 0xFFFF] * xls[e.x >> 16];
        o.y = pps[e.y & 0xFFFF] * xls[e.y >> 16];
        o.z = pps[e.z & 0xFFFF] * xls[e.z >> 16];
        o.w = pps[e.w & 0xFFFF] * xls[e.w >> 16];
        __builtin_nontemporal_store(o, (f32x4*)(ovbase + 4 * v));
    }

    // scalar tail (base table copy)
    int c = k0 + 4 * nv + tid;
    if (c < T) {
        uint32_t e = coltab[c];
        __builtin_nontemporal_store(pps[e & 0xFFFF] * xls[e >> 16], orow + c);
    }
}

extern "C" void kernel_launch(void* const* d_in, const int* in_sizes, int n_in,
                              void* d_out, int out_size, void* d_ws, size_t ws_size,
                              hipStream_t stream) {
    const float* x    = (const float*)d_in[0];
    const void*  mask = d_in[1];
    float*       out  = (float*)d_out;

    int rows = in_sizes[0] / DMAX;
    if (rows <= 0 || out_size <= 0) return;
    long long T = (long long)out_size / rows;

    // recover m from T(m) = m + m(m+1)/2 + m(m+1)(m+2)/6
    int m = -1;
    for (int mm = 0; mm <= DMAX; ++mm) {
        long long t = (long long)mm
                    + (long long)mm * (mm + 1) / 2
                    + (long long)mm * (mm + 1) * (mm + 2) / 6;
        if (t == T) { m = mm; break; }
    }
    if (m <= 0) return;

    int P    = m * (m + 1) / 2;
    int tpad = (int)((T + 3) & ~3LL);        // entries per table copy (16B mult)

    int*      idx     = (int*)d_ws;                       // 512 B
    uint32_t* pairtab = (uint32_t*)((char*)d_ws + 1024);  // ≤13 KB
    uint32_t* coltab  = (uint32_t*)((char*)d_ws + 32768); // 4 copies × tpad

    int sblocks = (P + 255) / 256;
    if (sblocks < 1) sblocks = 1;
    maskde_setup<<<sblocks, 256, 0, stream>>>(mask, m, idx, pairtab, coltab, P);

    int cblocks = (3 * tpad + 255) / 256;
    maskde_copies<<<cblocks, 256, 0, stream>>>(coltab, tpad, (int)T, m, P);

    size_t shmem = (size_t)(P + 1) * sizeof(float);
    maskde_expand<<<rows, BLK, shmem, stream>>>(x, idx, pairtab, coltab, tpad,
                                                out, m, (int)T, P);
}

// Round 6
// 147.463 us; speedup vs baseline: 1.0944x; 1.0944x over previous
//
#include <hip/hip_runtime.h>
#include <stdint.h>

#define DMAX 80
#define BLK  256
#define WPB  4     // waves per block, one row per wave

typedef float f32x4 __attribute__((ext_vector_type(4)));

// ---------------------------------------------------------------------------
// Setup kernel (single kernel, also builds the 3 shifted table copies):
//  - thread 0: detect mask dtype (bool8 / int32 / float32) via known m,
//    compact selected indices; write alignment-copy tail sentinels.
//  - grid-stride over pair ranks p in [0,P), P = m(m+1)/2:
//      pairtab[p] = i | j<<8
//      coltab[c]  = p | k<<16  where column c = pps[p] * xsel[k]
//        [0,m)      order-1: p = P (sentinel pps=1), k = c
//        [m, m+P)   order-2: p = rank,               k = m (sentinel x=1)
//        [m+P, T)   order-3: run over k in [j, m) for each pair (i,j)
//    Each entry is also written into shifted copies s=1..3 at
//    coltab[s*tpad + (c-s)] so any 16B-alignment class has aligned uint4
//    table loads.
// ---------------------------------------------------------------------------
__global__ void maskde_setup(const void* __restrict__ mask_raw, int m,
                             int* __restrict__ idx_out,
                             uint32_t* __restrict__ pairtab,
                             uint32_t* __restrict__ coltab, int tpad, int T,
                             int P) {
    int tid = blockIdx.x * blockDim.x + threadIdx.x;
    uint32_t sentinel = (uint32_t)P | ((uint32_t)m << 16);  // pps=1 * xls=1

    if (tid == 0) {
        const uint8_t* b8  = (const uint8_t*)mask_raw;
        const int*     b32 = (const int*)mask_raw;
        const float*   bf  = (const float*)mask_raw;
        int cnt = 0; bool ok = true;
        for (int i = 0; i < DMAX; ++i) { uint8_t v = b8[i]; if (v > 1) ok = false; cnt += (v != 0); }
        int mode;
        if (ok && cnt == m) {
            mode = 0;
        } else {
            cnt = 0; ok = true;
            for (int i = 0; i < DMAX; ++i) { int v = b32[i]; if (v != 0 && v != 1) ok = false; cnt += (v != 0); }
            mode = (ok && cnt == m) ? 1 : 2;
        }
        int k = 0;
        for (int i = 0; i < DMAX && k < m; ++i) {
            bool on = (mode == 0) ? (b8[i] != 0)
                    : (mode == 1) ? (b32[i] != 0)
                                  : (bf[i] != 0.0f);
            if (on) idx_out[k++] = i;
        }
        // tail sentinels for shifted copies: positions q in [T-s, tpad)
        for (int s = 1; s <= 3; ++s)
            for (int q = T - s; q < tpad; ++q)
                if (q >= 0) coltab[s * tpad + q] = sentinel;
    }

    int stride = gridDim.x * blockDim.x;
    for (int p = tid; p < P; p += stride) {
        int rem = p, i = 0;
        while (rem >= m - i) { rem -= (m - i); ++i; }
        int j = i + rem;

        pairtab[p] = (uint32_t)i | ((uint32_t)j << 8);

        // helper: write column c with value v into base + 3 shifted copies
        #define WR4(c, v) do {                                             \
            int _c = (c); uint32_t _v = (v);                               \
            coltab[_c] = _v;                                               \
            if (_c >= 1) coltab[tpad     + _c - 1] = _v;                   \
            if (_c >= 2) coltab[2 * tpad + _c - 2] = _v;                   \
            if (_c >= 3) coltab[3 * tpad + _c - 3] = _v;                   \
        } while (0)

        if (p < m)
            WR4(p, (uint32_t)P | ((uint32_t)p << 16));        // order-1
        WR4(m + p, (uint32_t)p | ((uint32_t)m << 16));        // order-2

        // order-3 run for pair (i,j)
        int mi = m - i;
        long long Si  = ((long long)m * (m + 1) * (m + 2)
                       - (long long)mi * (mi + 1) * (mi + 2)) / 6;
        int Rij = ((m - i) + (m - j + 1)) * (j - i) / 2;
        int base = m + P + (int)Si + Rij;
        uint32_t pk = (uint32_t)p;
        for (int k3 = j; k3 < m; ++k3)
            WR4(base + (k3 - j), pk | ((uint32_t)k3 << 16));
        #undef WR4
    }
}

// ---------------------------------------------------------------------------
// Main kernel: 4 waves per block, ONE ROW PER WAVE, each wave fully
// independent with its own LDS slice (xls[m+1], pps[P+1]).  No idle-lane
// prologue: each wave gathers and computes pair products for its own row.
// Barriers only separate symmetric per-wave phases (LDS visibility).
// Main loop: aligned uint4 table load + 8 LDS reads + aligned float4 store.
// ---------------------------------------------------------------------------
__global__ __launch_bounds__(BLK) void
maskde_expand(const float* __restrict__ x, const int* __restrict__ idx,
              const uint32_t* __restrict__ pairtab,
              const uint32_t* __restrict__ coltab, int tpad,
              float* __restrict__ out, int m, int T, int P, int rows) {
    extern __shared__ float smem[];
    const int XSTR  = m + 1;
    const int PPSTR = P + 1;

    const int wave = threadIdx.x >> 6;
    const int lane = threadIdx.x & 63;
    const int row  = blockIdx.x * WPB + wave;
    const bool active = (row < rows);

    float* xls = smem + wave * (XSTR + PPSTR);
    float* pps = xls + XSTR;

    // phase 0: per-wave gather of selected x values
    if (active && lane <= m)
        xls[lane] = (lane < m) ? x[row * DMAX + idx[lane]] : 1.0f;
    __syncthreads();

    // phase 1: per-wave pair products
    if (active) {
        for (int p = lane; p <= P; p += 64) {
            float v = 1.0f;
            if (p < P) {
                uint32_t ij = pairtab[p];
                v = xls[ij & 0xFF] * xls[(ij >> 8) & 0xFF];
            }
            pps[p] = v;
        }
    }
    __syncthreads();
    if (!active) return;

    float* orow = out + (size_t)row * (size_t)T;
    uintptr_t a0 = (uintptr_t)orow;
    int k0 = (int)(((16 - (a0 & 15)) & 15) >> 2);
    if (k0 > T) k0 = T;

    // scalar prologue (base table copy)
    if (lane < k0) {
        uint32_t e = coltab[lane];
        orow[lane] = pps[e & 0xFFFF] * xls[e >> 16];
    }

    const int nv = (T - k0) >> 2;
    const uint4* tbv = (const uint4*)(coltab + (size_t)k0 * (size_t)tpad);
    float* ovbase = orow + k0;

    for (int v = lane; v < nv; v += 64) {
        uint4 e = tbv[v];
        f32x4 o;
        o.x = pps[e.x & 0xFFFF] * xls[e.x >> 16];
        o.y = pps[e.y & 0xFFFF] * xls[e.y >> 16];
        o.z = pps[e.z & 0xFFFF] * xls[e.z >> 16];
        o.w = pps[e.w & 0xFFFF] * xls[e.w >> 16];
        *(f32x4*)(ovbase + 4 * v) = o;
    }

    // scalar tail (base table copy)
    int c = k0 + 4 * nv + lane;
    if (c < T) {
        uint32_t e = coltab[c];
        orow[c] = pps[e & 0xFFFF] * xls[e >> 16];
    }
}

extern "C" void kernel_launch(void* const* d_in, const int* in_sizes, int n_in,
                              void* d_out, int out_size, void* d_ws, size_t ws_size,
                              hipStream_t stream) {
    const float* x    = (const float*)d_in[0];
    const void*  mask = d_in[1];
    float*       out  = (float*)d_out;

    int rows = in_sizes[0] / DMAX;
    if (rows <= 0 || out_size <= 0) return;
    long long T = (long long)out_size / rows;

    // recover m from T(m) = m + m(m+1)/2 + m(m+1)(m+2)/6
    int m = -1;
    for (int mm = 0; mm <= DMAX; ++mm) {
        long long t = (long long)mm
                    + (long long)mm * (mm + 1) / 2
                    + (long long)mm * (mm + 1) * (mm + 2) / 6;
        if (t == T) { m = mm; break; }
    }
    if (m <= 0) return;

    int P    = m * (m + 1) / 2;
    int tpad = (int)((T + 3) & ~3LL);        // entries per table copy (16B mult)

    int*      idx     = (int*)d_ws;                       // 512 B
    uint32_t* pairtab = (uint32_t*)((char*)d_ws + 1024);  // ≤13 KB
    uint32_t* coltab  = (uint32_t*)((char*)d_ws + 32768); // 4 copies × tpad

    int sblocks = (P + 255) / 256;
    if (sblocks < 1) sblocks = 1;
    maskde_setup<<<sblocks, 256, 0, stream>>>(mask, m, idx, pairtab, coltab,
                                              tpad, (int)T, P);

    int blocks = (rows + WPB - 1) / WPB;
    size_t shmem = (size_t)WPB * (size_t)(m + 1 + P + 1) * sizeof(float);
    maskde_expand<<<blocks, BLK, shmem, stream>>>(x, idx, pairtab, coltab, tpad,
                                                  out, m, (int)T, P, rows);
}